// Round 8
// baseline (171.197 us; speedup 1.0000x reference)
//
#include <hip/hip_runtime.h>
#include <hip/hip_bf16.h>

typedef __bf16 bf16x8 __attribute__((ext_vector_type(8)));
typedef float  f32x4  __attribute__((ext_vector_type(4)));
typedef float  f32x16 __attribute__((ext_vector_type(16)));

#define NEG_BIG (-1e10f)

constexpr int FUSED_N = 4 * 32 * 32 * 256;  // 1048576

// ---------------------------------------------------------------------------
// fp32 inputs, no fp32 MFMA on CDNA4: split x = hi + lo (bf16 RNE + residual),
// scores ~= Ah*Bh + Ah*Bl + Al*Bh (drop lo*lo). Verified r2-r5.
// r3/r5: spill tripwire = WRITE_SIZE above the write floor.
// r5: total-minus-main ~90 us is fixed harness overhead.
// r10 rule: waves/SIMD = floor(512 / combined VGPR+AGPR), block-granular.
// r11: more occupancy via half-tiles -> slower (2x VMEM insts).
// r12/r6: source-level prefetch + SGB get re-narrowed by the allocator.
// r13/r7: 32x32 MFMA shape -> combined 120 <= 128, Occ 33%... dur UNCHANGED
//   (60.2 vs 60.3 vs 59.6 across r0/r2/r7). Occupancy irrelevant.
// r14 DIAGNOSIS (r0-r7, 8 pts): dur tracks TOTAL L2/L3 traffic across all
//   structures: ~640 MB (B-stream 256 + GEMV X re-read 256 + P 32 + att
//   writes 64+) in 60 us ~= 10.7 TB/s aggregate — the cache-path ceiling
//   (per-XCD X working set ~16 MB >> 4 MB L2 -> mostly L3). r5: +30%
//   traffic -> +56% dur. r4: +104 MB scratch -> +68% dur. TRAFFIC-BOUND.
// r14 (this round): kill the largest redundant stream. The fused GEMV
//   re-reads X(b,j) fp32 once per (i,j) = 32x redundancy = 256 MB. Move it
//   to a 4th kernel per (b,j): main writes 64-float w rows to workspace
//   (1 MB); fused_kernel reads X(b,j) ONCE (8 MB total) and computes the
//   32x64x256 mini-GEMM. Main k-loop/epilogue identical to r7.
// ---------------------------------------------------------------------------

// Async 16B global->LDS (DMA). Lane L lands at wave-uniform base + 16*L.
__device__ __forceinline__ void async_ld16(const void* g, void* l) {
    __builtin_amdgcn_global_load_lds(
        (const __attribute__((address_space(1))) void*)g,
        (__attribute__((address_space(3))) void*)l, 16, 0, 0);
}

// 16row x 32granule (16x256 bf16) tile for prep.
__device__ __forceinline__ int swzp(int row, int g) {
    return (row * 32 + (g ^ row)) * 8;   // row in [0,16)
}

// W fp32 -> hi/lo bf16 planes. 64 blocks x 256 threads x 4 elems.
__global__ __launch_bounds__(256) void convw_kernel(
    const float* __restrict__ W, __bf16* __restrict__ Wh, __bf16* __restrict__ Wl) {
    int idx = blockIdx.x * 256 + threadIdx.x;  // 0..16383
    float4 v = ((const float4*)W)[idx];
    float f[4] = {v.x, v.y, v.z, v.w};
    union { __bf16 b[4]; uint2 u; } H, L;
#pragma unroll
    for (int k = 0; k < 4; ++k) {
        __bf16 h = (__bf16)f[k];
        H.b[k] = h;
        L.b[k] = (__bf16)(f[k] - (float)h);
    }
    *(uint2*)&Wh[idx * 4] = H.u;
    *(uint2*)&Wl[idx * 4] = L.u;
}

// ---------------------------------------------------------------------------
// prep: convert 16 X rows -> Xh/Xl planes (global + LDS) and compute
// P = X @ W^T (split-3) -> Ph/Pl. 512 blocks; wave w handles col group w.
// ---------------------------------------------------------------------------
__global__ __launch_bounds__(256, 2) void prep_kernel(
    const float* __restrict__ Xf,
    const __bf16* __restrict__ Wh, const __bf16* __restrict__ Wl,
    __bf16* __restrict__ XhG, __bf16* __restrict__ XlG,
    __bf16* __restrict__ Ph, __bf16* __restrict__ Pl) {
    __shared__ __align__(16) __bf16 sXh[16 * 256];   // 8 KB
    __shared__ __align__(16) __bf16 sXl[16 * 256];   // 8 KB
    const int tid = threadIdx.x, rb = blockIdx.x;    // rows rb*16..rb*16+15

#pragma unroll
    for (int it = 0; it < 2; ++it) {
        int idx = it * 256 + tid;          // 512 granules
        int row = idx >> 5, g = idx & 31;
        const float* p = Xf + (rb * 16 + row) * 256 + g * 8;
        float4 v0 = *(const float4*)p;
        float4 v1 = *(const float4*)(p + 4);
        float f[8] = {v0.x, v0.y, v0.z, v0.w, v1.x, v1.y, v1.z, v1.w};
        union { __bf16 b[8]; uint4 u; } H, L;
#pragma unroll
        for (int k = 0; k < 8; ++k) {
            __bf16 h = (__bf16)f[k];
            H.b[k] = h;
            L.b[k] = (__bf16)(f[k] - (float)h);
        }
        int go = (rb * 16 + row) * 256 + g * 8;
        *(uint4*)&XhG[go] = H.u;
        *(uint4*)&XlG[go] = L.u;
        int o = swzp(row, g);
        *(uint4*)&sXh[o] = H.u;
        *(uint4*)&sXl[o] = L.u;
    }
    __syncthreads();

    const int lane = tid & 63, wave = tid >> 6, m = lane & 15, quad = lane >> 4;
    bf16x8 Ah[8], Al[8];
#pragma unroll
    for (int k0 = 0; k0 < 8; ++k0) {
        int o = swzp(m, k0 * 4 + quad);
        Ah[k0] = *(const bf16x8*)&sXh[o];
        Al[k0] = *(const bf16x8*)&sXl[o];
    }
    f32x4 acc[4];
    const f32x4 z = {0.f, 0.f, 0.f, 0.f};
#pragma unroll
    for (int n = 0; n < 4; ++n) acc[n] = z;
#pragma unroll
    for (int k0 = 0; k0 < 8; ++k0) {
#pragma unroll
        for (int n = 0; n < 4; ++n) {
            const int gcol = wave * 64 + n * 16 + m;
            const int wo = gcol * 256 + k0 * 32 + quad * 8;
            bf16x8 bh = *(const bf16x8*)&Wh[wo];
            bf16x8 bl = *(const bf16x8*)&Wl[wo];
            acc[n] = __builtin_amdgcn_mfma_f32_16x16x32_bf16(Ah[k0], bh, acc[n], 0, 0, 0);
            acc[n] = __builtin_amdgcn_mfma_f32_16x16x32_bf16(Ah[k0], bl, acc[n], 0, 0, 0);
            acc[n] = __builtin_amdgcn_mfma_f32_16x16x32_bf16(Al[k0], bh, acc[n], 0, 0, 0);
        }
    }
#pragma unroll
    for (int n = 0; n < 4; ++n)
#pragma unroll
        for (int r = 0; r < 4; ++r) {
            int row = rb * 16 + quad * 4 + r;
            int col = wave * 64 + n * 16 + m;
            float v = acc[n][r];
            __bf16 h = (__bf16)v;
            Ph[row * 256 + col] = h;
            Pl[row * 256 + col] = (__bf16)(v - (float)h);
        }
}

// ---------------------------------------------------------------------------
// main: 512 blocks = (b, i, jq), 512 threads = 8 waves, one j per wave.
// Stage P(b,i) hi/lo (64 KB, swizzled) via async DMA; ONE barrier; each wave
// runs 16 K-chunks (K=16) of 32x32x16 MFMAs into acc[2][2] f32x16 (64 AGPR).
// Combined regs ~120 <= 128 -> 2 blocks/CU. Epilogue: sigmoid + att store +
// w-reduce; w rows -> global workspace (fused GEMV moved to fused_kernel).
// ---------------------------------------------------------------------------
__global__ __launch_bounds__(512, 4) void main_kernel(
    const float* __restrict__ maskf, const float* __restrict__ aselff,
    const __bf16* __restrict__ XhG, const __bf16* __restrict__ XlG,
    const __bf16* __restrict__ PhG, const __bf16* __restrict__ PlG,
    float* __restrict__ wW, float* __restrict__ out) {
    __shared__ __align__(16) __bf16 sPh[64 * 256];   // 32 KB
    __shared__ __align__(16) __bf16 sPl[64 * 256];   // 32 KB
    __shared__ float sAs[64];                        // 256 B, aself row (i)
    const int tid = threadIdx.x;
    const int jq = blockIdx.x & 3;
    const int i  = (blockIdx.x >> 2) & 31;
    const int b  = blockIdx.x >> 7;
    const int lane = tid & 63, wave = tid >> 6;
    const int c31 = lane & 31, hi = lane >> 5, m15 = lane & 15;

    // Stage P(b,i) hi/lo. Each inst covers rows 2*insti..+1 (64 lanes x 16B);
    // 64 rows = 32 insts = 4 per wave. Slot (row,gs) gets granule gs^(row&15).
    const int pbase = (b * 32 + i) * 16384;
    {
        const int rowhalf = lane >> 5;     // 0..1
        const int gslot = lane & 31;
#pragma unroll
        for (int it = 0; it < 4; ++it) {
            const int insti = wave * 4 + it;           // 0..31
            const int row = insti * 2 + rowhalf;       // 0..63
            const int g = gslot ^ (row & 15);
            const int src = pbase + row * 256 + g * 8;
            async_ld16(&PhG[src], &sPh[insti * 512]);
            async_ld16(&PlG[src], &sPl[insti * 512]);
        }
    }

    // aself row for block-constant i -> LDS (broadcast reads in epilogue).
    if (tid < 64) sAs[tid] = aselff[(b * 32 + i) * 64 + tid];

    __syncthreads();   // DMA drained; the ONLY barrier

    const int j = jq * 8 + wave;
    const int xb = (b * 32 + j) * 16384;

    // B-frag (32x32x16): lane holds X[t = ng*32 + c31, h = kc*16 + hi*8 + e].
    const int boff = xb + c31 * 256 + hi * 8;
    // A-frag: lane holds P[s = rg*32 + c31, h = kc*16 + hi*8 + e] from
    // swizzled LDS: granule gg = kc*2 + hi lives at slot gg^(c31&15).
    const int arow0 = c31 * 256;          // rg=0 row base (elements)
    const int arow1 = (32 + c31) * 256;   // rg=1

    f32x16 acc00, acc01, acc10, acc11;
#pragma unroll
    for (int e = 0; e < 16; ++e) { acc00[e] = 0.f; acc01[e] = 0.f; acc10[e] = 0.f; acc11[e] = 0.f; }

#pragma unroll
    for (int kc = 0; kc < 16; ++kc) {
        bf16x8 Bh0 = *(const bf16x8*)&XhG[boff + kc * 16];
        bf16x8 Bh1 = *(const bf16x8*)&XhG[boff + 32 * 256 + kc * 16];
        bf16x8 Bl0 = *(const bf16x8*)&XlG[boff + kc * 16];
        bf16x8 Bl1 = *(const bf16x8*)&XlG[boff + 32 * 256 + kc * 16];
        const int slot = ((kc * 2 + hi) ^ m15) * 8;
        bf16x8 Ah0 = *(const bf16x8*)&sPh[arow0 + slot];
        bf16x8 Ah1 = *(const bf16x8*)&sPh[arow1 + slot];
        bf16x8 Al0 = *(const bf16x8*)&sPl[arow0 + slot];
        bf16x8 Al1 = *(const bf16x8*)&sPl[arow1 + slot];

        acc00 = __builtin_amdgcn_mfma_f32_32x32x16_bf16(Ah0, Bh0, acc00, 0, 0, 0);
        acc00 = __builtin_amdgcn_mfma_f32_32x32x16_bf16(Ah0, Bl0, acc00, 0, 0, 0);
        acc00 = __builtin_amdgcn_mfma_f32_32x32x16_bf16(Al0, Bh0, acc00, 0, 0, 0);
        acc01 = __builtin_amdgcn_mfma_f32_32x32x16_bf16(Ah0, Bh1, acc01, 0, 0, 0);
        acc01 = __builtin_amdgcn_mfma_f32_32x32x16_bf16(Ah0, Bl1, acc01, 0, 0, 0);
        acc01 = __builtin_amdgcn_mfma_f32_32x32x16_bf16(Al0, Bh1, acc01, 0, 0, 0);
        acc10 = __builtin_amdgcn_mfma_f32_32x32x16_bf16(Ah1, Bh0, acc10, 0, 0, 0);
        acc10 = __builtin_amdgcn_mfma_f32_32x32x16_bf16(Ah1, Bl0, acc10, 0, 0, 0);
        acc10 = __builtin_amdgcn_mfma_f32_32x32x16_bf16(Al1, Bh0, acc10, 0, 0, 0);
        acc11 = __builtin_amdgcn_mfma_f32_32x32x16_bf16(Ah1, Bh1, acc11, 0, 0, 0);
        acc11 = __builtin_amdgcn_mfma_f32_32x32x16_bf16(Ah1, Bl1, acc11, 0, 0, 0);
        acc11 = __builtin_amdgcn_mfma_f32_32x32x16_bf16(Al1, Bh1, acc11, 0, 0, 0);
    }

    // ---- wave-local epilogue ----
    // C/D: col t = ng*32 + c31; row s = rg*32 + (r&3) + 8*(r>>2) + 4*hi.
    const float* mrow = maskf + (b * 32 + j) * 64;
    float madd[2];
#pragma unroll
    for (int ng = 0; ng < 2; ++ng)
        madd[ng] = (1.0f - mrow[ng * 32 + c31]) * NEG_BIG;

    float part[2] = {0.f, 0.f};
    float* outA = out + FUSED_N + ((size_t)((b * 32 + i) * 32 + j)) * 4096;
#pragma unroll
    for (int rg = 0; rg < 2; ++rg)
#pragma unroll
        for (int r = 0; r < 16; ++r) {
            const int s = rg * 32 + (r & 3) + 8 * (r >> 2) + 4 * hi;
            const float as_ = sAs[s];
            const float a0v = (rg == 0) ? acc00[r] : acc10[r];
            const float a1v = (rg == 0) ? acc01[r] : acc11[r];
            {
                float x = a0v + madd[0];
                float a = 1.0f / (1.0f + __expf(-x));
                outA[s * 64 + c31] = a;
                part[0] += as_ * a;
            }
            {
                float x = a1v + madd[1];
                float a = 1.0f / (1.0f + __expf(-x));
                outA[s * 64 + 32 + c31] = a;
                part[1] += as_ * a;
            }
        }
    // reduce over the two k-halves (lanes l and l^32 share t = c31)
    part[0] += __shfl_xor(part[0], 32, 64);
    part[1] += __shfl_xor(part[1], 32, 64);
    if (hi == 0) {
        float* wg = wW + ((size_t)((b * 32 + i) * 32 + j)) * 64;
        wg[c31] = part[0];
        wg[32 + c31] = part[1];
    }
}

// ---------------------------------------------------------------------------
// fused: 256 blocks = (b*32+j, h-half), 128 threads (one h each). Reads the
// w rows for all 32 i (8 KB -> LDS) and X(b,j) fp32 ONCE, computes
// fused[i,h] = sum_t w[i,t] * X[t,h]. X traffic: 8 MB total (was 256 MB as
// a per-(i,j) GEMV inside main). sw reads broadcast (bank-free).
// ---------------------------------------------------------------------------
__global__ __launch_bounds__(128) void fused_kernel(
    const float* __restrict__ Xf, const float* __restrict__ wW,
    float* __restrict__ out) {
    __shared__ float sw[32][64];   // 8 KB
    const int bj = blockIdx.x >> 1;      // b*32 + j
    const int hh = blockIdx.x & 1;
    const int tid = threadIdx.x;         // 0..127
    const int b = bj >> 5, j = bj & 31;

#pragma unroll
    for (int k = 0; k < 16; ++k) {
        const int idx = k * 128 + tid;   // 0..2047
        const int ii = idx >> 6, t = idx & 63;
        sw[ii][t] = wW[((size_t)(b * 1024 + ii * 32 + j)) * 64 + t];
    }
    __syncthreads();

    const int h = hh * 128 + tid;
    const float* Xg = Xf + (size_t)bj * 16384 + h;
    float acc[32];
#pragma unroll
    for (int ii = 0; ii < 32; ++ii) acc[ii] = 0.f;
#pragma unroll 8
    for (int t = 0; t < 64; ++t) {
        const float xv = Xg[t * 256];
#pragma unroll
        for (int ii = 0; ii < 32; ++ii) acc[ii] += sw[ii][t] * xv;
    }
    float* og = out + (size_t)(b * 1024 + j) * 256 + h;
#pragma unroll
    for (int ii = 0; ii < 32; ++ii) og[(size_t)ii * 8192] = acc[ii];
}

extern "C" void kernel_launch(void* const* d_in, const int* in_sizes, int n_in,
                              void* d_out, int out_size, void* d_ws, size_t ws_size,
                              hipStream_t stream) {
    const float* X     = (const float*)d_in[0];  // [4,32,64,256] fp32
    const float* mask  = (const float*)d_in[1];  // [4,32,64]
    const float* aself = (const float*)d_in[2];  // [4,32,64]
    const float* W     = (const float*)d_in[3];  // [256,256]
    float* out = (float*)d_out;

    __bf16* ws = (__bf16*)d_ws;
    const size_t NX = 2097152, NW = 65536;
    __bf16* Xh = ws;
    __bf16* Xl = Xh + NX;
    __bf16* Ph = Xl + NX;
    __bf16* Pl = Ph + NX;
    __bf16* Wh = Pl + NX;
    __bf16* Wl = Wh + NW;
    float*  wW = (float*)(Wl + NW);   // 4*32*32*64 fp32 = 1 MB

    convw_kernel<<<dim3(64), dim3(256), 0, stream>>>(W, Wh, Wl);
    prep_kernel<<<dim3(512), dim3(256), 0, stream>>>(X, Wh, Wl, Xh, Xl, Ph, Pl);
    main_kernel<<<dim3(512), dim3(512), 0, stream>>>(
        mask, aself, Xh, Xl, Ph, Pl, wW, out);
    fused_kernel<<<dim3(256), dim3(128), 0, stream>>>(X, wW, out);
}